// Round 5
// baseline (308.778 us; speedup 1.0000x reference)
//
#include <hip/hip_runtime.h>
#include <utility>

// ---------------------------------------------------------------------------
// Compile-time Clebsch-Gordan coefficients (Racah formula), fp64 -> fp32.
// Split into 4 tables (one per l1) to stay under clang's constexpr step limit.
// ---------------------------------------------------------------------------
namespace cg {

constexpr double FACT[14] = {
  1.0, 1.0, 2.0, 6.0, 24.0, 120.0, 720.0, 5040.0, 40320.0, 362880.0,
  3628800.0, 39916800.0, 479001600.0, 6227020800.0
};

constexpr double csqrt(double x){
  double g = x > 1.0 ? x : 1.0;
  for (int i = 0; i < 64; ++i) g = 0.5 * (g + x / g);
  return g;
}
constexpr int cabs_(int x){ return x < 0 ? -x : x; }
constexpr int imax_(int a, int b){ return a > b ? a : b; }
constexpr int imin_(int a, int b){ return a < b ? a : b; }

constexpr double cg_coeff(int j1,int m1,int j2,int m2,int j,int m){
  if (m1 + m2 != m || j < cabs_(j1 - j2) || j > j1 + j2) return 0.0;
  double pre = csqrt((2.0*j + 1.0) * FACT[j1+j2-j] * FACT[j+j1-j2] * FACT[j+j2-j1]
                     / FACT[j1+j2+j+1]);
  pre *= csqrt(FACT[j+m] * FACT[j-m] * FACT[j1+m1] * FACT[j1-m1]
             * FACT[j2+m2] * FACT[j2-m2]);
  double s = 0.0;
  for (int k = 0; k <= j1 + j2 - j; ++k){
    int d2 = j1 - m1 - k, d3 = j2 + m2 - k, d4 = j - j2 + m1 + k, d5 = j - j1 - m2 + k;
    if (d2 < 0 || d3 < 0 || d4 < 0 || d5 < 0) continue;
    double denom = FACT[k] * FACT[j1+j2-j-k] * FACT[d2] * FACT[d3] * FACT[d4] * FACT[d5];
    s += ((k & 1) ? -1.0 : 1.0) / denom;
  }
  return pre * s;
}

struct Tab1 { float c[4][7][7][7]; };  // [l2][l][m1+l1][m2+l2] for fixed l1
constexpr Tab1 make_tab1(int l1){
  Tab1 t{};
  for (int l2 = 0; l2 < 4; ++l2)
    for (int l = 0; l < 7; ++l)
      for (int i1 = 0; i1 < 2*l1 + 1; ++i1)
        for (int i2 = 0; i2 < 2*l2 + 1; ++i2){
          int m1 = i1 - l1, m2 = i2 - l2, m = m1 + m2;
          if (m < -l || m > l) continue;
          t.c[l2][l][i1][i2] = (float)cg_coeff(l1, m1, l2, m2, l, m);
        }
  return t;
}
constexpr Tab1 T0 = make_tab1(0);
constexpr Tab1 T1 = make_tab1(1);
constexpr Tab1 T2 = make_tab1(2);
constexpr Tab1 T3 = make_tab1(3);
constexpr float getc(int l1,int l2,int l,int i1,int i2){
  return l1 == 0 ? T0.c[l2][l][i1][i2]
       : l1 == 1 ? T1.c[l2][l][i1][i2]
       : l1 == 2 ? T2.c[l2][l][i1][i2]
       :           T3.c[l2][l][i1][i2];
}

// Fragment (l1,l2) pair lists in gelib order (l1-major), per output l.
constexpr int NP[7]    = {4, 9, 11, 10, 6, 3, 1};          // tau_l
constexpr int IOFF[4]  = {0, 1, 4, 9};                     // input offset per l (pair units)
constexpr int P1[7][11] = {
  {0,1,2,3,0,0,0,0,0,0,0},
  {0,1,1,1,2,2,2,3,3,0,0},
  {0,1,1,1,2,2,2,2,3,3,3},
  {0,1,1,2,2,2,3,3,3,3,0},
  {1,2,2,3,3,3,0,0,0,0,0},
  {2,3,3,0,0,0,0,0,0,0,0},
  {3,0,0,0,0,0,0,0,0,0,0}
};
constexpr int P2[7][11] = {
  {0,1,2,3,0,0,0,0,0,0,0},
  {1,0,1,2,1,2,3,2,3,0,0},
  {2,1,2,3,0,1,2,3,1,2,3},
  {3,2,3,1,2,3,0,1,2,3,0},
  {3,2,3,1,2,3,0,0,0,0,0},
  {3,2,3,0,0,0,0,0,0,0,0},
  {3,0,0,0,0,0,0,0,0,0,0}
};

// ---- Row table: 49 output rows (l, mi), each 2*NP[l] floats, laid out
// consecutively in the 512-float per-element output. ----
constexpr int ROWN = 49;
struct Rows { int l[ROWN]; int mi[ROWN]; int off[ROWN]; int sz[ROWN]; };
constexpr Rows make_rows(){
  Rows r{}; int idx = 0; int off = 0;
  for (int l = 0; l < 7; ++l)
    for (int mi = 0; mi < 2*l + 1; ++mi){
      r.l[idx] = l; r.mi[idx] = mi; r.off[idx] = off; r.sz[idx] = 2*NP[l];
      off += 2*NP[l]; ++idx;
    }
  return r;
}
constexpr Rows RW = make_rows();

// ---- Item table: every (row, pair) item emits exactly 2 floats (fr,fi) at
// even offset off = RW.off[r] + 2t, so items NEVER straddle a 32-float
// (128 B) boundary. Chunk the 512-float output into 16 chunks of exactly
// 32 floats (= one 128 B line); each chunk is exactly 16 items. Every
// copy-out store is a float4 into a fully-written, 128B-aligned line:
// no partial cache lines -> no DRAM read-modify-write.  [verified R3: -73us]
// ----
constexpr int NCH = 16;        // 16 chunks x 32 floats = 512
constexpr int CW  = 32;        // floats per element per chunk
struct CItems { int r[16]; int t[16]; };
struct AllItems { CItems ch[NCH]; };
constexpr AllItems make_items(){
  AllItems a{};
  int n[NCH] = {};
  for (int r = 0; r < ROWN; ++r){
    int l = RW.l[r];
    for (int t = 0; t < NP[l]; ++t){
      int off = RW.off[r] + 2*t;
      int c = off / CW;
      a.ch[c].r[n[c]] = r; a.ch[c].t[n[c]] = t; ++n[c];
    }
  }
  return a;
}
constexpr AllItems AI = make_items();

} // namespace cg

// ---------------------------------------------------------------------------
// static_for: guarantees every loop index is a compile-time constant
// ---------------------------------------------------------------------------
template<class F, int... Is>
__device__ __forceinline__ void sfor_impl(F&& f, std::integer_sequence<int, Is...>){
  (f(std::integral_constant<int, Is>{}), ...);
}
template<int N, class F>
__device__ __forceinline__ void sfor(F&& f){
  sfor_impl(static_cast<F&&>(f), std::make_integer_sequence<int, N>{});
}

typedef float f32x4 __attribute__((ext_vector_type(4)));

// ---------------------------------------------------------------------------
// lgkm-only workgroup barrier: LDS visibility without draining in-flight
// HBM stores (a full __syncthreads emits s_waitcnt vmcnt(0) which serializes
// the entire store stream into the barrier). Memory clobbers on both sides
// stop the compiler moving ds ops across the raw s_barrier.
// ---------------------------------------------------------------------------
__device__ __forceinline__ void bar_lgkm(){
  asm volatile("s_waitcnt lgkmcnt(0)" ::: "memory");
  __builtin_amdgcn_s_barrier();
  asm volatile("" ::: "memory");
}

// ---------------------------------------------------------------------------
// Kernel (R5): R3 structure + 2-LANES-PER-ELEMENT occupancy split.
//
// R3 (verified 281 us) was capped at 2048 waves = 2 waves/SIMD by the
// 1-element-per-lane decomposition; store-latency / store-register-reuse
// stalls had no co-resident waves to hide behind. R5 assigns each element to
// a LANE PAIR: lane 2e+h computes the parity-h half of each chunk's 16 items
// (compile-time code halves execute exec-masked; per-wave issue count is
// unchanged, chip-wide VALU doubles but VALU was ~7 us). Waves: 2048 -> 4096
// = 4 waves/SIMD, 16 waves/CU; stores per wave halve; in-flight store bytes
// chip-wide double. Barriers / swizzle / regular stores: identical to R3.
// (R4's confounded {no-barrier + NT-store} change regressed and is reverted.)
//
// Per wave: 32 elements. LDS buffer per wave per parity: 32 floats x 32
// elements = 4 KB; block = 4 waves x 2 x 4 KB = 32 KB -> grid 1024 blocks =
// 4 blocks/CU (LDS would allow 5; waves cap at 4 with 16 waves/CU... VGPR
// ~<=128 keeps 4 waves/SIMD resident).
//
// Swizzle (32 columns): value (elem e, float j) at buf[j*32 + (e ^ K(j))],
// K(j) = 4*(j>>2) in {0,4,...,28}.
//   writes (j=loc const, 32 active lanes of one parity): col = e ^ K is a
//     permutation of 0..31 -> 32 distinct banks, 1 lane/bank (free).
//   reads (j=4*c4+i, K=4*c4, e=e0+8*kk, kk fixed per instr): col bits
//     {0,1}=e0, {2}=e0_2^c4_0, {3,4}=kk^c4_{1,2} -> 64 lanes cover all 32
//     cols exactly 2x (free). K identical for fr/fi (loc even) and for the
//     4 dwords of each float4.
//
// Copy-out: e0 = lane>>3, c4 = lane&7; 4 iters of one float4 store cover
// 32 elem x 32 floats; each wave store = 8 elements x one FULL 128 B line.
// ---------------------------------------------------------------------------
__global__ __launch_bounds__(256) void cgprod_kernel(
    const float* __restrict__ x0, const float* __restrict__ x1,
    const float* __restrict__ x2, const float* __restrict__ x3,
    float* __restrict__ out, int B)
{
  constexpr int EPW  = 32;                  // elements per wave
  constexpr int WBUF = cg::CW * EPW;        // 1024 floats per wave buffer
  __shared__ float lds[4][2][WBUF];         // 32 KB

  const int tid  = threadIdx.x;
  const int wid  = tid >> 6;
  const int lane = tid & 63;
  const int e_in = lane >> 1;               // element within wave (0..31)
  const int h    = lane & 1;                // parity: which half of the items
  const int wave_base = blockIdx.x * 128 + EPW * wid;
  const int b  = wave_base + e_in;
  const int bc = b < B ? b : B - 1;         // clamp (B%128==0 in practice)
  const bool full = (wave_base + EPW <= B);

  float xr[16], xi[16];  // per-l pair offsets 0,1,4,9 (sizes 1,3,5,7)
  { float2 v = *reinterpret_cast<const float2*>(x0 + (size_t)bc * 2);
    xr[0] = v.x; xi[0] = v.y; }
  { const float2* p = reinterpret_cast<const float2*>(x1 + (size_t)bc * 6);
    sfor<3>([&](auto I){ constexpr int i = decltype(I)::value;
      float2 v = p[i]; xr[1+i] = v.x; xi[1+i] = v.y; }); }
  { const float2* p = reinterpret_cast<const float2*>(x2 + (size_t)bc * 10);
    sfor<5>([&](auto I){ constexpr int i = decltype(I)::value;
      float2 v = p[i]; xr[4+i] = v.x; xi[4+i] = v.y; }); }
  { const float2* p = reinterpret_cast<const float2*>(x3 + (size_t)bc * 14);
    sfor<7>([&](auto I){ constexpr int i = decltype(I)::value;
      float2 v = p[i]; xr[9+i] = v.x; xi[9+i] = v.y; }); }

  const int e0 = lane >> 3;        // element (within wave) in copy-out
  const int c4 = lane & 7;         // float4 index within the 32-float chunk

  sfor<cg::NCH>([&](auto CC){
    constexpr int c = decltype(CC)::value;
    constexpr int G = c * cg::CW;             // global float offset of chunk
    float* buf = &lds[wid][c & 1][0];

    // --- compute this chunk's 16 items; lane-pair splits by item parity ---
    sfor<16>([&](auto IC){
      constexpr int it = decltype(IC)::value;
      if (h == (it & 1)){
        constexpr int r  = cg::AI.ch[c].r[it];
        constexpr int t  = cg::AI.ch[c].t[it];
        constexpr int l  = cg::RW.l[r];
        constexpr int m  = cg::RW.mi[r] - l;
        constexpr int l1 = cg::P1[l][t];
        constexpr int l2 = cg::P2[l][t];
        constexpr int loc = (cg::RW.off[r] + 2*t) - G;  // 0..30, even
        constexpr int K   = 4 * (loc >> 2);             // same for loc, loc+1
        constexpr int m1lo = cg::imax_(-l1, m - l2);
        constexpr int m1hi = cg::imin_( l1, m + l2);
        float fr = 0.f, fi = 0.f;
        sfor<m1hi - m1lo + 1>([&](auto KC){
          constexpr int m1 = m1lo + decltype(KC)::value;
          constexpr int m2 = m - m1;
          constexpr float cc = cg::getc(l1, l2, l, m1 + l1, m2 + l2);
          if constexpr (cc != 0.0f){
            constexpr int ia = cg::IOFF[l1] + m1 + l1;
            constexpr int ib = cg::IOFF[l2] + m2 + l2;
            const float ar = xr[ia], ai = xi[ia];
            const float br = xr[ib], bi = xi[ib];
            const float tr = fmaf(-ai, bi, ar * br);  // re(x_l1 * x_l2)
            const float ti = fmaf( ai, br, ar * bi);  // im(x_l1 * x_l2)
            fr = fmaf(cc, tr, fr);
            fi = fmaf(cc, ti, fi);
          }
        });
        const int col = e_in ^ K;
        buf[(loc    ) * EPW + col] = fr;
        buf[(loc + 1) * EPW + col] = fi;
      }
    });

    bar_lgkm();   // LDS visible; prior chunk's HBM stores stay in flight

    // --- coalesced float4 copy-out: 4 iters cover 32 elem x 32 floats ---
    if (full){
      sfor<4>([&](auto KK){
        constexpr int kk = decltype(KK)::value;
        const int el  = e0 + 8 * kk;
        const int col = el ^ (4 * c4);
        f32x4 v;
        v.x = buf[(4*c4 + 0) * EPW + col];
        v.y = buf[(4*c4 + 1) * EPW + col];
        v.z = buf[(4*c4 + 2) * EPW + col];
        v.w = buf[(4*c4 + 3) * EPW + col];
        *reinterpret_cast<f32x4*>(out + (size_t)(wave_base + el) * 512 + G + 4*c4) = v;
      });
    } else {
      sfor<4>([&](auto KK){
        constexpr int kk = decltype(KK)::value;
        const int el  = e0 + 8 * kk;
        const int col = el ^ (4 * c4);
        if (wave_base + el < B){
          f32x4 v;
          v.x = buf[(4*c4 + 0) * EPW + col];
          v.y = buf[(4*c4 + 1) * EPW + col];
          v.z = buf[(4*c4 + 2) * EPW + col];
          v.w = buf[(4*c4 + 3) * EPW + col];
          *reinterpret_cast<f32x4*>(out + (size_t)(wave_base + el) * 512 + G + 4*c4) = v;
        }
      });
    }
    // no second barrier: at bar(c+1) every wave has finished copyout(c), so
    // compute(c+2) reusing this buffer is ordered. Last chunk: just end.
  });
}

extern "C" void kernel_launch(void* const* d_in, const int* in_sizes, int n_in,
                              void* d_out, int out_size, void* d_ws, size_t ws_size,
                              hipStream_t stream)
{
  const float* x0 = (const float*)d_in[0];
  const float* x1 = (const float*)d_in[1];
  const float* x2 = (const float*)d_in[2];
  const float* x3 = (const float*)d_in[3];
  float* out = (float*)d_out;

  const int B = in_sizes[0] / 2;  // x0 is (B, 1, 2)
  const int block = 256;          // 4 waves, 128 elements per block
  const int grid = (B + 127) / 128;
  cgprod_kernel<<<grid, block, 0, stream>>>(x0, x1, x2, x3, out, B);
}

// Round 6
// 285.110 us; speedup vs baseline: 1.0830x; 1.0830x over previous
//
#include <hip/hip_runtime.h>
#include <utility>

// ---------------------------------------------------------------------------
// Compile-time Clebsch-Gordan coefficients (Racah formula), fp64 -> fp32.
// Split into 4 tables (one per l1) to stay under clang's constexpr step limit.
// ---------------------------------------------------------------------------
namespace cg {

constexpr double FACT[14] = {
  1.0, 1.0, 2.0, 6.0, 24.0, 120.0, 720.0, 5040.0, 40320.0, 362880.0,
  3628800.0, 39916800.0, 479001600.0, 6227020800.0
};

constexpr double csqrt(double x){
  double g = x > 1.0 ? x : 1.0;
  for (int i = 0; i < 64; ++i) g = 0.5 * (g + x / g);
  return g;
}
constexpr int cabs_(int x){ return x < 0 ? -x : x; }
constexpr int imax_(int a, int b){ return a > b ? a : b; }
constexpr int imin_(int a, int b){ return a < b ? a : b; }

constexpr double cg_coeff(int j1,int m1,int j2,int m2,int j,int m){
  if (m1 + m2 != m || j < cabs_(j1 - j2) || j > j1 + j2) return 0.0;
  double pre = csqrt((2.0*j + 1.0) * FACT[j1+j2-j] * FACT[j+j1-j2] * FACT[j+j2-j1]
                     / FACT[j1+j2+j+1]);
  pre *= csqrt(FACT[j+m] * FACT[j-m] * FACT[j1+m1] * FACT[j1-m1]
             * FACT[j2+m2] * FACT[j2-m2]);
  double s = 0.0;
  for (int k = 0; k <= j1 + j2 - j; ++k){
    int d2 = j1 - m1 - k, d3 = j2 + m2 - k, d4 = j - j2 + m1 + k, d5 = j - j1 - m2 + k;
    if (d2 < 0 || d3 < 0 || d4 < 0 || d5 < 0) continue;
    double denom = FACT[k] * FACT[j1+j2-j-k] * FACT[d2] * FACT[d3] * FACT[d4] * FACT[d5];
    s += ((k & 1) ? -1.0 : 1.0) / denom;
  }
  return pre * s;
}

struct Tab1 { float c[4][7][7][7]; };  // [l2][l][m1+l1][m2+l2] for fixed l1
constexpr Tab1 make_tab1(int l1){
  Tab1 t{};
  for (int l2 = 0; l2 < 4; ++l2)
    for (int l = 0; l < 7; ++l)
      for (int i1 = 0; i1 < 2*l1 + 1; ++i1)
        for (int i2 = 0; i2 < 2*l2 + 1; ++i2){
          int m1 = i1 - l1, m2 = i2 - l2, m = m1 + m2;
          if (m < -l || m > l) continue;
          t.c[l2][l][i1][i2] = (float)cg_coeff(l1, m1, l2, m2, l, m);
        }
  return t;
}
constexpr Tab1 T0 = make_tab1(0);
constexpr Tab1 T1 = make_tab1(1);
constexpr Tab1 T2 = make_tab1(2);
constexpr Tab1 T3 = make_tab1(3);
constexpr float getc(int l1,int l2,int l,int i1,int i2){
  return l1 == 0 ? T0.c[l2][l][i1][i2]
       : l1 == 1 ? T1.c[l2][l][i1][i2]
       : l1 == 2 ? T2.c[l2][l][i1][i2]
       :           T3.c[l2][l][i1][i2];
}

// Fragment (l1,l2) pair lists in gelib order (l1-major), per output l.
constexpr int NP[7]    = {4, 9, 11, 10, 6, 3, 1};          // tau_l
constexpr int IOFF[4]  = {0, 1, 4, 9};                     // input offset per l (pair units)
constexpr int P1[7][11] = {
  {0,1,2,3,0,0,0,0,0,0,0},
  {0,1,1,1,2,2,2,3,3,0,0},
  {0,1,1,1,2,2,2,2,3,3,3},
  {0,1,1,2,2,2,3,3,3,3,0},
  {1,2,2,3,3,3,0,0,0,0,0},
  {2,3,3,0,0,0,0,0,0,0,0},
  {3,0,0,0,0,0,0,0,0,0,0}
};
constexpr int P2[7][11] = {
  {0,1,2,3,0,0,0,0,0,0,0},
  {1,0,1,2,1,2,3,2,3,0,0},
  {2,1,2,3,0,1,2,3,1,2,3},
  {3,2,3,1,2,3,0,1,2,3,0},
  {3,2,3,1,2,3,0,0,0,0,0},
  {3,2,3,0,0,0,0,0,0,0,0},
  {3,0,0,0,0,0,0,0,0,0,0}
};

// ---- Row table: 49 output rows (l, mi), each 2*NP[l] floats, laid out
// consecutively in the 512-float per-element output. ----
constexpr int ROWN = 49;
struct Rows { int l[ROWN]; int mi[ROWN]; int off[ROWN]; int sz[ROWN]; };
constexpr Rows make_rows(){
  Rows r{}; int idx = 0; int off = 0;
  for (int l = 0; l < 7; ++l)
    for (int mi = 0; mi < 2*l + 1; ++mi){
      r.l[idx] = l; r.mi[idx] = mi; r.off[idx] = off; r.sz[idx] = 2*NP[l];
      off += 2*NP[l]; ++idx;
    }
  return r;
}
constexpr Rows RW = make_rows();

// ---- Item table: every (row, pair) item emits exactly 2 floats (fr,fi) at
// even offset off = RW.off[r] + 2t. Chunk the 512-float output into 8 chunks
// of exactly 64 floats (= two 128 B lines, 256 B); each chunk is exactly 32
// items, in increasing-offset order (item i of a chunk sits at loc = 2i), so
// item pairs (2p, 2p+1) form a full float4 at loc 4p.
//   R3 verified (CW=32): full-line stores kill DRAM read-modify-write (-73us).
//   R6 hypothesis (CW=64): 256 B per element per store period doubles the
//   DRAM-visible write granularity -> better row-buffer locality.
// ----
constexpr int NCH = 8;         // 8 chunks x 64 floats = 512
constexpr int CW  = 64;        // floats per element per chunk
struct CItems { int r[32]; int t[32]; };
struct AllItems { CItems ch[NCH]; };
constexpr AllItems make_items(){
  AllItems a{};
  int n[NCH] = {};
  for (int r = 0; r < ROWN; ++r){
    int l = RW.l[r];
    for (int t = 0; t < NP[l]; ++t){
      int off = RW.off[r] + 2*t;
      int c = off / CW;
      a.ch[c].r[n[c]] = r; a.ch[c].t[n[c]] = t; ++n[c];
    }
  }
  return a;
}
constexpr AllItems AI = make_items();

} // namespace cg

// ---------------------------------------------------------------------------
// static_for: guarantees every loop index is a compile-time constant
// ---------------------------------------------------------------------------
template<class F, int... Is>
__device__ __forceinline__ void sfor_impl(F&& f, std::integer_sequence<int, Is...>){
  (f(std::integral_constant<int, Is>{}), ...);
}
template<int N, class F>
__device__ __forceinline__ void sfor(F&& f){
  sfor_impl(static_cast<F&&>(f), std::make_integer_sequence<int, N>{});
}

typedef float f32x4 __attribute__((ext_vector_type(4)));

// ---------------------------------------------------------------------------
// lgkm-only workgroup barrier: LDS visibility without draining in-flight
// HBM stores (a full __syncthreads emits s_waitcnt vmcnt(0) which serializes
// the entire store stream into the barrier). Memory clobbers on both sides
// stop the compiler moving ds ops across the raw s_barrier.
// ---------------------------------------------------------------------------
__device__ __forceinline__ void bar_lgkm(){
  asm volatile("s_waitcnt lgkmcnt(0)" ::: "memory");
  __builtin_amdgcn_s_barrier();
  asm volatile("" ::: "memory");
}

// ---------------------------------------------------------------------------
// Kernel (R6): R3 structure with CW 32 -> 64 (256 B per element per period).
//
// Single variable vs R3 (verified 281 us): DRAM-visible write granularity.
// R3 wrote each element's 2 KB row as 16 temporally-separated 128 B lines at
// 2 KB stride; resident blocks' dirty-line working set >> L2/XCD, so lines
// evict before neighbors arrive -> DRAM row-buffer thrash (effective ~2.8
// TB/s vs the fill's 6.3 on the same buffer). Supporting evidence: R3's
// full-line fix was -73 us (line-level fragmentation); R4's NT bypass of
// cache aggregation was +17 us. CW=64 doubles the contiguous segment.
//
// Budget identical to R3: 256 threads, 1 element/lane, LDS 64 KB static ->
// 2 blocks/CU = 8 waves/CU; barriers 8 chunks x 2 = 16 (R3: 16 x 1); LDS
// traffic identical but now 16 ds_write_b128 + 16 ds_read_b128 per lane-
// chunk instead of 32+32 b32 (fewer issue slots); stores 16 dwordx4 per
// lane-chunk (total 128, same).
//
// LDS layout (float4-granular): value (elem e, float4-row p in 0..15) at
//   lds4[p*256 + (e ^ 4p)].
//   writes (p const, 256 threads): col = tid ^ 4p -- per wave a permutation
//     of 64 distinct cols -> 8 lanes per col%8 class -> conflict-free b128.
//   reads (lane: j4r = tid&15, e0 = tid>>4; e = e0 + 16k): col = e ^ 4*j4r;
//     per instruction cols = {bits0,1 = lane>>4} x {bits2..5 = const ^
//     (lane&15)} = 64 distinct -> conflict-free b128.
//
// Single buffer, 2 lgkm-barriers per chunk: writes(c), bar (all writes
// visible), reads(c)+stores(c), bar (all reads done -> writes(c+1) WAR-safe;
// stores stay in flight, no vmcnt drain).
//
// Copy-out: each wave instr = 4 elements x fully-written aligned 256 B.
// ---------------------------------------------------------------------------
__global__ __launch_bounds__(256) void cgprod_kernel(
    const float* __restrict__ x0, const float* __restrict__ x1,
    const float* __restrict__ x2, const float* __restrict__ x3,
    float* __restrict__ out, int B)
{
  __shared__ f32x4 lds4[16 * 256];          // 65536 B == static limit

  const int tid = threadIdx.x;
  const int block_base = blockIdx.x * 256;
  const int b = block_base + tid;
  const int bc = b < B ? b : B - 1;   // clamp: all threads must reach barriers
  const bool full = (block_base + 256 <= B);  // B%256==0 in practice -> true

  float xr[16], xi[16];  // per-l pair offsets 0,1,4,9 (sizes 1,3,5,7)
  { float2 v = *reinterpret_cast<const float2*>(x0 + (size_t)bc * 2);
    xr[0] = v.x; xi[0] = v.y; }
  { const float2* p = reinterpret_cast<const float2*>(x1 + (size_t)bc * 6);
    sfor<3>([&](auto I){ constexpr int i = decltype(I)::value;
      float2 v = p[i]; xr[1+i] = v.x; xi[1+i] = v.y; }); }
  { const float2* p = reinterpret_cast<const float2*>(x2 + (size_t)bc * 10);
    sfor<5>([&](auto I){ constexpr int i = decltype(I)::value;
      float2 v = p[i]; xr[4+i] = v.x; xi[4+i] = v.y; }); }
  { const float2* p = reinterpret_cast<const float2*>(x3 + (size_t)bc * 14);
    sfor<7>([&](auto I){ constexpr int i = decltype(I)::value;
      float2 v = p[i]; xr[9+i] = v.x; xi[9+i] = v.y; }); }

  const int e0  = tid >> 4;        // element group in copy-out (0..15)
  const int j4r = tid & 15;        // float4 row this lane reads (0..15)

  sfor<cg::NCH>([&](auto CC){
    constexpr int c = decltype(CC)::value;
    constexpr int G = c * cg::CW;             // global float offset of chunk

    // --- compute this chunk's 32 items as 16 float4s, stage into LDS ---
    sfor<16>([&](auto PC){
      constexpr int p = decltype(PC)::value;  // float4 row = loc>>2
      float q0, q1, q2, q3;
      sfor<2>([&](auto HH){
        constexpr int hh = decltype(HH)::value;
        constexpr int it = 2*p + hh;
        constexpr int r  = cg::AI.ch[c].r[it];
        constexpr int t  = cg::AI.ch[c].t[it];
        constexpr int l  = cg::RW.l[r];
        constexpr int m  = cg::RW.mi[r] - l;
        constexpr int l1 = cg::P1[l][t];
        constexpr int l2 = cg::P2[l][t];
        constexpr int loc = (cg::RW.off[r] + 2*t) - G;  // expect 4p + 2*hh
        static_assert(loc == 4*p + 2*hh, "item order broke float4 pairing");
        constexpr int m1lo = cg::imax_(-l1, m - l2);
        constexpr int m1hi = cg::imin_( l1, m + l2);
        float fr = 0.f, fi = 0.f;
        sfor<m1hi - m1lo + 1>([&](auto KC){
          constexpr int m1 = m1lo + decltype(KC)::value;
          constexpr int m2 = m - m1;
          constexpr float cc = cg::getc(l1, l2, l, m1 + l1, m2 + l2);
          if constexpr (cc != 0.0f){
            constexpr int ia = cg::IOFF[l1] + m1 + l1;
            constexpr int ib = cg::IOFF[l2] + m2 + l2;
            const float ar = xr[ia], ai = xi[ia];
            const float br = xr[ib], bi = xi[ib];
            const float tr = fmaf(-ai, bi, ar * br);  // re(x_l1 * x_l2)
            const float ti = fmaf( ai, br, ar * bi);  // im(x_l1 * x_l2)
            fr = fmaf(cc, tr, fr);
            fi = fmaf(cc, ti, fi);
          }
        });
        if constexpr (hh == 0){ q0 = fr; q1 = fi; } else { q2 = fr; q3 = fi; }
      });
      f32x4 v; v.x = q0; v.y = q1; v.z = q2; v.w = q3;
      lds4[p * 256 + (tid ^ (4*p))] = v;    // ds_write_b128, conflict-free
    });

    bar_lgkm();   // all writes visible; prior chunks' HBM stores in flight

    // --- coalesced float4 copy-out: 16 iters cover 256 elem x 64 floats ---
    if (full){
      sfor<16>([&](auto KK){
        constexpr int kk = decltype(KK)::value;
        const int e   = e0 + 16 * kk;
        const int col = e ^ (4 * j4r);
        f32x4 v = lds4[j4r * 256 + col];    // ds_read_b128, conflict-free
        *reinterpret_cast<f32x4*>(out + (size_t)(block_base + e) * 512 + G + 4*j4r) = v;
      });
    } else {
      sfor<16>([&](auto KK){
        constexpr int kk = decltype(KK)::value;
        const int e   = e0 + 16 * kk;
        const int col = e ^ (4 * j4r);
        if (block_base + e < B){
          f32x4 v = lds4[j4r * 256 + col];
          *reinterpret_cast<f32x4*>(out + (size_t)(block_base + e) * 512 + G + 4*j4r) = v;
        }
      });
    }

    // WAR barrier: all waves' reads done -> next chunk may overwrite LDS.
    // (lgkm-only: stores stay in flight.) Skip after the last chunk.
    if constexpr (c + 1 < cg::NCH) bar_lgkm();
  });
}

extern "C" void kernel_launch(void* const* d_in, const int* in_sizes, int n_in,
                              void* d_out, int out_size, void* d_ws, size_t ws_size,
                              hipStream_t stream)
{
  const float* x0 = (const float*)d_in[0];
  const float* x1 = (const float*)d_in[1];
  const float* x2 = (const float*)d_in[2];
  const float* x3 = (const float*)d_in[3];
  float* out = (float*)d_out;

  const int B = in_sizes[0] / 2;  // x0 is (B, 1, 2)
  const int block = 256;
  const int grid = (B + block - 1) / block;
  cgprod_kernel<<<grid, block, 0, stream>>>(x0, x1, x2, x3, out, B);
}